// Round 5
// baseline (270.034 us; speedup 1.0000x reference)
//
#include <hip/hip_runtime.h>

// ---------- constants ----------
#define B_   16
#define C_   256
#define OC_  256
#define H_   64
#define W_   64

typedef __attribute__((ext_vector_type(8))) __bf16 bf16x8;
typedef __attribute__((ext_vector_type(4))) float  f32x4;

__device__ __forceinline__ short f2bf(float f) {
    unsigned u = __float_as_uint(f);
    u += 0x7fffu + ((u >> 16) & 1u);
    return (short)(u >> 16);
}
__device__ __forceinline__ unsigned pk2(float a, float b) {
    return (unsigned(f2bf(a)) & 0xffffu) | (unsigned(f2bf(b)) << 16);
}
__device__ __forceinline__ void gll16(const void* g, void* l) {
    __builtin_amdgcn_global_load_lds(
        (const __attribute__((address_space(1))) unsigned int*)g,
        (__attribute__((address_space(3))) unsigned int*)l,
        16, 0, 0);
}

// ---------- kernel 1: x (fp32 NCHW) -> xt (bf16 [b][y][x][c]) + pool partials ----------
// Grid (16,16): block = (4-row y-group g, sample b). Pool partials accumulate in
// registers across the 4 rows -> ONE plain store per (c,sj) per block. No atomics.
// pp2 is [b][16 g][4 sj][256 c] = 1 MiB (sized correctly this time).
__global__ __launch_bounds__(256) void k_transpose_pool(
        const float* __restrict__ x, short* __restrict__ xt,
        float* __restrict__ pp2) {
    int g = blockIdx.x, b = blockIdx.y, t = threadIdx.x;
    int lane = t & 63, wv = t >> 6;
    int xq = lane & 15, cw = lane >> 4;
    __shared__ float tile[64 * 67];

    float racc[4][4];
    #pragma unroll
    for (int i = 0; i < 4; ++i)
        #pragma unroll
        for (int j = 0; j < 4; ++j) racc[i][j] = 0.f;

    for (int iy = 0; iy < 4; ++iy) {
        int y = g * 4 + iy;
        for (int cc = 0; cc < 4; ++cc) {
            int cbase = cc * 64;
            if (iy | cc) __syncthreads();
            #pragma unroll
            for (int r = 0; r < 4; ++r) {
                int c_l = r * 16 + wv * 4 + cw;
                float4 v = *(const float4*)&x[(((size_t)b * C_ + cbase + c_l) * H_ + y) * W_ + xq * 4];
                float* tp = &tile[c_l * 67 + xq * 4];
                tp[0] = v.x; tp[1] = v.y; tp[2] = v.z; tp[3] = v.w;
                float s = v.x + v.y + v.z + v.w;
                s += __shfl_xor(s, 1);
                s += __shfl_xor(s, 2);          // 4-lane group holds 16-x sum
                racc[cc][r] += s;
            }
            __syncthreads();
            #pragma unroll
            for (int r2 = 0; r2 < 2; ++r2) {
                int u = r2 * 256 + t;
                int xx = u >> 3, cgl = u & 7;
                float f[8];
                #pragma unroll
                for (int j = 0; j < 8; ++j) f[j] = tile[(cgl * 8 + j) * 67 + xx];
                uint4 pkv;
                pkv.x = pk2(f[0], f[1]); pkv.y = pk2(f[2], f[3]);
                pkv.z = pk2(f[4], f[5]); pkv.w = pk2(f[6], f[7]);
                *(uint4*)&xt[(((size_t)b * H_ + y) * W_ + xx) * C_ + cbase + cgl * 8] = pkv;
            }
        }
    }
    if ((lane & 3) == 0) {
        int sj = xq >> 2;
        #pragma unroll
        for (int cc = 0; cc < 4; ++cc)
            #pragma unroll
            for (int r = 0; r < 4; ++r) {
                int c = cc * 64 + r * 16 + wv * 4 + cw;
                pp2[((b * 16 + g) * 4 + sj) * 256 + c] = racc[cc][r];
            }
    }
}

// ---------- kernel 2: routing head -> r[b][k][c] ----------
__global__ __launch_bounds__(256) void k_route(
        const float* __restrict__ pp2, const float* __restrict__ rconv_w,
        const float* __restrict__ rconv_b, const float* __restrict__ fc_w,
        const float* __restrict__ fc_b, float* __restrict__ r_buf) {
    int b = blockIdx.x;
    int t = threadIdx.x;
    __shared__ float pl[16][257];
    __shared__ float y1[256];

    #pragma unroll
    for (int q = 0; q < 16; ++q) {      // q = si*4+sj
        int si = q >> 2, sj = q & 3;
        float s = 0.f;
        #pragma unroll
        for (int gg = 0; gg < 4; ++gg)
            s += pp2[((b * 16 + si * 4 + gg) * 4 + sj) * 256 + t];
        pl[q][t] = s * (1.0f / 256.0f);
    }
    __syncthreads();
    {
        int rcc = t >> 4, ss = t & 15;
        float acc = rconv_b[rcc];
        #pragma unroll 8
        for (int c = 0; c < 256; ++c)
            acc += pl[ss][c] * rconv_w[rcc * 256 + c];
        y1[rcc * 16 + ss] = fmaxf(acc, 0.f);
    }
    __syncthreads();
    for (int e0 = 0; e0 < 768; e0 += 256) {
        int e = e0 + t;
        float acc = fc_b[e];
        #pragma unroll 8
        for (int q = 0; q < 256; ++q)
            acc += y1[q] * fc_w[(size_t)e * 256 + q];
        acc = fmaxf(acc, 0.f);
        r_buf[(size_t)b * 768 + e] = 1.f / (1.f + __expf(-acc));
    }
}

// ---------- kernel 3: combine experts -> wcomb[b][o][tap][c] (bf16) ----------
__global__ __launch_bounds__(256) void k_combine(
        const float* __restrict__ E, const float* __restrict__ r_buf,
        short* __restrict__ wcomb) {
    int o = blockIdx.x;        // 0..255
    int b0 = blockIdx.y * 8;   // 8 b's per block
    int t = threadIdx.x;
    __shared__ float eT[3][2304];
    #pragma unroll
    for (int k = 0; k < 3; ++k)
        #pragma unroll
        for (int q = 0; q < 9; ++q)
            eT[k][q * 256 + t] = E[((size_t)k * OC_ + o) * 2304 + q * 256 + t];
    __syncthreads();
    int c = t;
    #pragma unroll
    for (int bb = 0; bb < 8; ++bb) {
        int b = b0 + bb;
        float r0 = r_buf[(size_t)b * 768 + c];
        float r1 = r_buf[(size_t)b * 768 + 256 + c];
        float r2 = r_buf[(size_t)b * 768 + 512 + c];
        short* wo = wcomb + ((size_t)(b * OC_ + o) * 9) * C_;
        #pragma unroll
        for (int tap = 0; tap < 9; ++tap) {
            float v = r0 * eT[0][c * 9 + tap] + r1 * eT[1][c * 9 + tap]
                    + r2 * eT[2][c * 9 + tap];
            wo[tap * C_ + c] = f2bf(v);
        }
    }
}

// ---------- kernel 4 (R3-proven): conv, resident x-window + A LDS double-buffer ----------
// M=128 o, N=128 pos (2 rows), per cc-chunk (64 ch): stage window once,
// loop 9 taps with A prefetched into the other buffer.
// LDS = 32KB window + 2x16KB A = 65536 B -> 2 blocks/CU.
__global__ __launch_bounds__(256, 2) void k_conv(
        const short* __restrict__ xt, const short* __restrict__ wcomb,
        float* __restrict__ out, const short* __restrict__ zbuf) {
    int lin  = blockIdx.x;
    int work = (lin & 7) * 128 + (lin >> 3);   // XCD-contiguous: 2 samples/XCD
    int b      = work >> 6;
    int o_base = ((work >> 5) & 1) * 128;
    int y0     = (work & 31) * 2;

    int t = threadIdx.x;
    int lane = t & 63, w = t >> 6;
    int quad = lane >> 4, l15 = lane & 15;

    __shared__ __align__(16) short win[4 * 64 * 64];      // [wrow][xc][slot8][8ch] 32 KB
    __shared__ __align__(16) short abuf[2][128 * 64];     // [o_l][slot8][8ch] 2x16 KB

    // window staging sources (8 rounds x 256 threads = 2048 tasks, halo rows -> zbuf)
    const short* wsrc[8];
    #pragma unroll
    for (int r = 0; r < 8; ++r) {
        int u = r * 256 + t;
        int pos = u >> 3, sp = u & 7;
        int wrow = pos >> 6, xc = pos & 63;
        int yy = y0 - 1 + wrow;
        int ss = sp ^ (xc & 7);                 // XOR swizzle at source
        wsrc[r] = ((unsigned)yy < 64u)
            ? xt + (((size_t)b * 64 + yy) * 64 + xc) * 256 + ss * 8
            : zbuf;
    }
    // A staging sources (4 rounds)
    const short* asrc[4];
    #pragma unroll
    for (int r = 0; r < 4; ++r) {
        int u = r * 256 + t;
        int o_l = u >> 3, sp = u & 7;
        int ss = sp ^ (o_l & 7);
        asrc[r] = wcomb + (((size_t)b * 256 + o_base + o_l) * 9) * 256 + ss * 8;
    }

    int m_base = (w & 1) * 64;
    int n_base = (w >> 1) * 64;
    int ry0 = n_base >> 6;                       // output row within pair (0/1)
    int xb[4];
    #pragma unroll
    for (int nb = 0; nb < 4; ++nb) xb[nb] = nb * 16 + l15;

    f32x4 acc[4][4];
    #pragma unroll
    for (int i = 0; i < 4; ++i)
        #pragma unroll
        for (int j = 0; j < 4; ++j) acc[i][j] = {0.f, 0.f, 0.f, 0.f};

    for (int cc = 0; cc < 4; ++cc) {
        int ccOff = cc * 64;
        #pragma unroll
        for (int r = 0; r < 8; ++r)
            gll16(wsrc[r] + ccOff, &win[(r * 256 + w * 64) * 8]);
        #pragma unroll
        for (int r = 0; r < 4; ++r)
            gll16(asrc[r] + ccOff, &abuf[0][(r * 256 + w * 64) * 8]);
        __syncthreads();

        #pragma unroll
        for (int tap = 0; tap < 9; ++tap) {
            const int ti = tap / 3, tj = tap % 3;
            const int cur = tap & 1;
            if (tap < 8) {   // prefetch next tap's A into the other buffer
                int off2 = (tap + 1) * 256 + ccOff;
                #pragma unroll
                for (int r = 0; r < 4; ++r)
                    gll16(asrc[r] + off2, &abuf[cur ^ 1][(r * 256 + w * 64) * 8]);
            }
            int wrb = (ry0 + ti) * 4096;         // window row base (shorts)
            #pragma unroll
            for (int s = 0; s < 2; ++s) {
                int slog = s * 4 + quad;
                bf16x8 af[4], bv[4];
                #pragma unroll
                for (int mb = 0; mb < 4; ++mb) {
                    int o_l = m_base + mb * 16 + l15;
                    af[mb] = *(const bf16x8*)&abuf[cur][o_l * 64 + ((slog ^ (o_l & 7)) * 8)];
                }
                #pragma unroll
                for (int nb = 0; nb < 4; ++nb) {
                    int xc = xb[nb] + (tj - 1);
                    bool ok = ((unsigned)xc < 64u);
                    int xs = ok ? xc : 0;
                    bf16x8 v = *(const bf16x8*)&win[wrb + xs * 64 + ((slog ^ (xs & 7)) * 8)];
                    bf16x8 zz = {};
                    bv[nb] = ok ? v : zz;        // column halo is zero
                }
                #pragma unroll
                for (int mb = 0; mb < 4; ++mb)
                    #pragma unroll
                    for (int nb = 0; nb < 4; ++nb)
                        acc[mb][nb] = __builtin_amdgcn_mfma_f32_16x16x32_bf16(
                            af[mb], bv[nb], acc[mb][nb], 0, 0, 0);
            }
            __syncthreads();   // drains prefetch vmcnt + protects buffer swap
        }
    }

    #pragma unroll
    for (int mb = 0; mb < 4; ++mb) {
        #pragma unroll
        for (int nb = 0; nb < 4; ++nb) {
            int p  = n_base + nb * 16 + l15;
            int yy = y0 + (p >> 6);
            int xx = p & 63;
            #pragma unroll
            for (int rg = 0; rg < 4; ++rg) {
                int o = o_base + m_base + mb * 16 + quad * 4 + rg;
                out[(((size_t)b * OC_ + o) * H_ + yy) * W_ + xx] = acc[mb][nb][rg];
            }
        }
    }
}

// ---------- launcher ----------
extern "C" void kernel_launch(void* const* d_in, const int* in_sizes, int n_in,
                              void* d_out, int out_size, void* d_ws, size_t ws_size,
                              hipStream_t stream) {
    const float* x       = (const float*)d_in[0];
    const float* E       = (const float*)d_in[1];
    const float* rconv_w = (const float*)d_in[2];
    const float* rconv_b = (const float*)d_in[3];
    const float* fc_w    = (const float*)d_in[4];
    const float* fc_b    = (const float*)d_in[5];
    float* out = (float*)d_out;

    char* ws = (char*)d_ws;
    short* xt    = (short*)(ws);                 // 32 MiB
    short* wcomb = (short*)(ws + 33554432);      // 18 MiB -> ends 52428800
    float* pp2   = (float*)(ws + 52428800);      // 1 MiB pool partials -> ends 53477376
    float* rbuf  = (float*)(ws + 53477376);      // 48 KiB -> ends 53526528
    short* zbuf  = (short*)(ws + 53526528);      // 1 KiB zeros

    hipMemsetAsync(zbuf, 0, 1024, stream);

    k_transpose_pool<<<dim3(16, 16), 256, 0, stream>>>(x, xt, pp2);
    k_route<<<dim3(16), 256, 0, stream>>>(pp2, rconv_w, rconv_b, fc_w, fc_b, rbuf);
    k_combine<<<dim3(256, 2), 256, 0, stream>>>(E, rbuf, wcomb);
    k_conv<<<dim3(1024), 256, 0, stream>>>(xt, wcomb, out, zbuf);
}